// Round 1
// baseline (1751.721 us; speedup 1.0000x reference)
//
#include <hip/hip_runtime.h>
#include <hip/hip_bf16.h>
#include <math.h>

// ---------------------------------------------------------------------------
// Dims (fixed per reference)
// ---------------------------------------------------------------------------
#define BATCH   16384
#define D_IN    1024
#define H1_DIM  512
#define H2_DIM  256
#define H3_DIM  128
#define D_CBP   2048
#define H_C     1024
#define CLASSES 10
#define SLOPE   0.2f

typedef short v8s __attribute__((ext_vector_type(8)));
typedef float v4f __attribute__((ext_vector_type(4)));
typedef unsigned short u16;
typedef unsigned int   u32;

__device__ __forceinline__ float b2f(unsigned short u) {
  return __uint_as_float(((unsigned)u) << 16);
}
__device__ __forceinline__ u16 f2b(float f) {
  __hip_bfloat16 h = __float2bfloat16(f);   // RNE
  return __builtin_bit_cast(unsigned short, h);
}

// async 16B global->LDS (direct-to-shared DMA). LDS dest = wave-uniform base
// + lane*16 -> LDS layout is forced packed lane-order.
__device__ __forceinline__ void g2l16(const void* g, void* l) {
  __builtin_amdgcn_global_load_lds(
      (const __attribute__((address_space(1))) void*)g,
      (__attribute__((address_space(3))) void*)l, 16, 0, 0);
}

// ---------------------------------------------------------------------------
// bf16 MFMA GEMM (m97 structure): C[M,N] = lrelu(A[M,K] @ Bt[N,K]^T + bias)
// Tile 128x128, BK=32, 256 threads (4 waves, 2x2 of 64x64), 16 MFMA/wave/step.
// Granule rotation swizzle applied at the GLOBAL address so both A- and
// B-fragment ds_read_b128 are exactly 2 lanes/bank (free).
// ---------------------------------------------------------------------------
__global__ __launch_bounds__(256) void gemm_bf16(
    const u16* __restrict__ A,   // [M][K] bf16
    const u16* __restrict__ Bt,  // [N][K] bf16  (weights pre-transposed)
    const float* __restrict__ bias,
    u16* __restrict__ C,         // [M][N] bf16
    int M, int N, int K)
{
  __shared__ __align__(16) short Asb[128 * 32];
  __shared__ __align__(16) short Bsb[128 * 32];

  const int tid  = threadIdx.x;
  const int wave = tid >> 6, lane = tid & 63;
  const int wm = wave >> 1, wn = wave & 1;
  const int u = lane & 15, quad = lane >> 4;
  const int m0 = blockIdx.y * 128, n0 = blockIdx.x * 128;

  const int g_log = ((lane & 3) - ((lane >> 3) & 3)) & 3;
  const int srow  = wave * 32 + (lane >> 2);
  const u16* gA0 = A  + (size_t)(m0 + srow)      * K + g_log * 8;
  const u16* gA1 = A  + (size_t)(m0 + srow + 16) * K + g_log * 8;
  const u16* gB0 = Bt + (size_t)(n0 + srow)      * K + g_log * 8;
  const u16* gB1 = Bt + (size_t)(n0 + srow + 16) * K + g_log * 8;
  short* lA0 = &Asb[(wave * 32)      * 32];
  short* lA1 = &Asb[(wave * 32 + 16) * 32];
  short* lB0 = &Bsb[(wave * 32)      * 32];
  short* lB1 = &Bsb[(wave * 32 + 16) * 32];

  const int gran = (quad + (u >> 1)) & 3;
  int offA[4], offB[4];
#pragma unroll
  for (int i = 0; i < 4; ++i) {
    offA[i] = (wm * 64 + i * 16 + u) * 32 + gran * 8;
    offB[i] = (wn * 64 + i * 16 + u) * 32 + gran * 8;
  }

  v4f acc[4][4];
#pragma unroll
  for (int i = 0; i < 4; ++i)
#pragma unroll
    for (int j = 0; j < 4; ++j) acc[i][j] = (v4f){0.f, 0.f, 0.f, 0.f};

  for (int k0 = 0; k0 < K; k0 += 32) {
    __syncthreads();
    g2l16(gA0 + k0, lA0);
    g2l16(gA1 + k0, lA1);
    g2l16(gB0 + k0, lB0);
    g2l16(gB1 + k0, lB1);
    __syncthreads();
    v8s a[4], b[4];
#pragma unroll
    for (int i = 0; i < 4; ++i) a[i] = *(const v8s*)&Asb[offA[i]];
#pragma unroll
    for (int j = 0; j < 4; ++j) b[j] = *(const v8s*)&Bsb[offB[j]];
#pragma unroll
    for (int i = 0; i < 4; ++i)
#pragma unroll
      for (int j = 0; j < 4; ++j)
        acc[i][j] = __builtin_amdgcn_mfma_f32_16x16x32_bf16(a[i], b[j], acc[i][j], 0, 0, 0);
  }

  // C/D layout (m89-verified): col = lane&15, row = quad*4 + reg
  float bcol[4];
#pragma unroll
  for (int j = 0; j < 4; ++j) bcol[j] = bias[n0 + wn * 64 + j * 16 + u];
#pragma unroll
  for (int i = 0; i < 4; ++i)
#pragma unroll
    for (int r = 0; r < 4; ++r) {
      const size_t ro = (size_t)(m0 + wm * 64 + i * 16 + quad * 4 + r) * N
                        + n0 + wn * 64 + u;
#pragma unroll
      for (int j = 0; j < 4; ++j) {
        float v = acc[i][j][r] + bcol[j];
        v = v >= 0.f ? v : SLOPE * v;
        C[ro + j * 16] = f2b(v);
      }
    }
}

// ---------------------------------------------------------------------------
// cast fp32 -> bf16, two sources in one launch (X then Centers)
// ---------------------------------------------------------------------------
#define CAST_NB (BATCH * D_IN / 4 / 256)   // blocks per source
__global__ __launch_bounds__(256) void cast2_bf16(
    const float* __restrict__ srcA, const float* __restrict__ srcB,
    u16* __restrict__ dst)
{
  const int bx = blockIdx.x;
  const float* s = (bx < CAST_NB) ? srcA : srcB;
  const int i = ((bx < CAST_NB) ? bx : bx - CAST_NB) * 256 + threadIdx.x;
  u16* d = dst + ((bx < CAST_NB) ? 0 : (size_t)BATCH * D_IN);
  const float4 v = ((const float4*)s)[i];
  __align__(8) u16 o[4] = {f2b(v.x), f2b(v.y), f2b(v.z), f2b(v.w)};
  *(uint2*)(d + (size_t)i * 4) = *(uint2*)o;
}

// ---------------------------------------------------------------------------
// transpose + cast, all 4 weights in one launch (z selects the matrix):
// W[K][N] fp32 -> Wt[N][K] bf16.  32x32 tiles via LDS.
// ---------------------------------------------------------------------------
__global__ __launch_bounds__(256) void transpose_cast4(
    const float* __restrict__ W1, u16* __restrict__ W1t,
    const float* __restrict__ W2, u16* __restrict__ W2t,
    const float* __restrict__ W3, u16* __restrict__ W3t,
    const float* __restrict__ Wc1, u16* __restrict__ Wc1t)
{
  __shared__ float tile[32][33];
  const int z = blockIdx.z;
  const float* W; u16* Wt; int K, N;
  if      (z == 0) { W = W1;  Wt = W1t;  K = D_IN;   N = H1_DIM; }
  else if (z == 1) { W = W2;  Wt = W2t;  K = H1_DIM; N = H2_DIM; }
  else if (z == 2) { W = W3;  Wt = W3t;  K = H2_DIM; N = H3_DIM; }
  else             { W = Wc1; Wt = Wc1t; K = D_CBP;  N = H_C;    }
  const int k0 = blockIdx.x * 32, n0 = blockIdx.y * 32;
  if (k0 >= K || n0 >= N) return;
  const int tx = threadIdx.x & 31, ty = threadIdx.x >> 5;
#pragma unroll
  for (int s = 0; s < 4; ++s) {
    const int k = ty * 4 + s;
    tile[k][tx] = W[(size_t)(k0 + k) * N + n0 + tx];
  }
  __syncthreads();
#pragma unroll
  for (int s = 0; s < 4; ++s) {
    const int n = ty * 4 + s;
    Wt[(size_t)(n0 + n) * K + k0 + tx] = f2b(tile[tx][n]);
  }
}

// ---------------------------------------------------------------------------
// Compact bilinear pooling — sparse outer-product scatter form.
//   cbp[b, (h1_i + h2_j) & 2047] += (s1_i ex_i)(s2_j ec_j),  i,j in [0,128)
// 16,384 MACs/row (exact: bsk has <=128 nonzeros, the old dense-gather form
// multiplied by zero 15/16 of the time => 16x arithmetic + ~2.5x DS cut).
// Mapping: thread t owns i = t&127; its wave owns j-range (t>>7)*64..+64.
// b-side operands (h2_j, bv_j) live one-per-lane and are delivered per
// iteration via v_readlane (compile-time k from the unrolled loop) -> SGPR,
// so the ONLY DS op in the loop is the ds_add_f32 scatter into the 8 KiB
// f32 accumulator. f32 accumulation (better than the old f16 path).
// ---------------------------------------------------------------------------
__global__ __launch_bounds__(256) void cbp_kernel(
    const u16* __restrict__ E3,     // [2*BATCH][128] bf16
    const int* __restrict__ h1, const float* __restrict__ s1,
    const int* __restrict__ h2, const float* __restrict__ s2,
    u16* __restrict__ cbp)          // [BATCH][2048] bf16
{
  __shared__ float acc[D_CBP];                  // 8 KiB

  const int b = blockIdx.x, t = threadIdx.x;
  const int i  = t & 127;                       // a-side index (per lane)
  const int jl = ((t >> 7) << 6) + (t & 63);    // this lane's b-side element

  // zero the accumulator (8 f32 per thread, conflict-free b128 stores)
  *(float4*)&acc[t * 8]     = (float4){0.f, 0.f, 0.f, 0.f};
  *(float4*)&acc[t * 8 + 4] = (float4){0.f, 0.f, 0.f, 0.f};

  // a-side: per-lane scalar held in VGPR
  const float a  = b2f(E3[(size_t)b * H3_DIM + i]) * s1[i];
  const int   hi = h1[i];

  // b-side: lane l of this wave holds element j = jbase + l
  const float bv = b2f(E3[(size_t)(BATCH + b) * H3_DIM + jl]) * s2[jl];
  const int   h2l    = h2[jl];
  const int   bvbits = (int)__builtin_bit_cast(u32, bv);

  __syncthreads();

#pragma unroll
  for (int k = 0; k < 64; ++k) {
    const int   hk = __builtin_amdgcn_readlane(h2l, k);      // SGPR
    const float bk = __builtin_bit_cast(
        float, (u32)__builtin_amdgcn_readlane(bvbits, k));   // SGPR
    const int bin = (hi + hk) & (D_CBP - 1);
    atomicAdd(&acc[bin], a * bk);                            // ds_add_f32
  }

  __syncthreads();

  // write out: thread t owns q = 8t..8t+7
  const float* ap = &acc[t * 8];
  v8s ov;
#pragma unroll
  for (int c = 0; c < 8; ++c) ov[c] = (short)f2b(ap[c]);
  *(v8s*)(cbp + (size_t)b * D_CBP + t * 8) = ov;
}

// ---------------------------------------------------------------------------
// Head: logits = Z[B,1024](bf16) @ Wc2[1024,10] + bc2; softmax -> fp32 out.
// ---------------------------------------------------------------------------
__global__ __launch_bounds__(256) void head_softmax(
    const u16* __restrict__ Z, const float* __restrict__ Wc2,
    const float* __restrict__ bc2, float* __restrict__ out)
{
  const int row  = blockIdx.x * 4 + (threadIdx.x >> 6);
  const int lane = threadIdx.x & 63;

  float acc[CLASSES];
#pragma unroll
  for (int c = 0; c < CLASSES; ++c) acc[c] = 0.f;

  const u16* z = Z + (size_t)row * H_C;
  for (int k = lane; k < H_C; k += 64) {
    const float zv = b2f(z[k]);
    const float* w = Wc2 + (size_t)k * CLASSES;
#pragma unroll
    for (int c = 0; c < CLASSES; ++c) acc[c] += zv * w[c];
  }
#pragma unroll
  for (int c = 0; c < CLASSES; ++c) {
#pragma unroll
    for (int off = 32; off > 0; off >>= 1)
      acc[c] += __shfl_down(acc[c], off);
  }
  if (lane == 0) {
    float l[CLASSES], mx = -1e30f;
#pragma unroll
    for (int c = 0; c < CLASSES; ++c) { l[c] = acc[c] + bc2[c]; mx = fmaxf(mx, l[c]); }
    float s = 0.f;
#pragma unroll
    for (int c = 0; c < CLASSES; ++c) { l[c] = __expf(l[c] - mx); s += l[c]; }
    const float inv = 1.f / s;
#pragma unroll
    for (int c = 0; c < CLASSES; ++c) out[(size_t)row * CLASSES + c] = l[c] * inv;
  }
}

// ---------------------------------------------------------------------------
// Launcher.  Workspace (1 MiB = 1<<20), lifetime-packed, ~126 MiB:
//   Xb   @ 0       [32768,1024] bf16 = 64 MiB   (dead after G1)
//   CBPb @ 0       [16384,2048] bf16 = 64 MiB   (overlays Xb)
//   E1b  @ 64 MiB  [32768, 512] bf16 = 32 MiB   (dead after G2)
//   Zb   @ 64 MiB  [16384,1024] bf16 = 32 MiB   (overlays E1b)
//   E2b  @ 96 MiB  [32768, 256] bf16 = 16 MiB
//   E3b  @ 112 MiB [32768, 128] bf16 =  8 MiB
//   W1t @120M  W2t @121M  W3t @121.5M  Wc1t @122M (bf16, transposed)
// ---------------------------------------------------------------------------
extern "C" void kernel_launch(void* const* d_in, const int* in_sizes, int n_in,
                              void* d_out, int out_size, void* d_ws, size_t ws_size,
                              hipStream_t stream) {
  const float* X       = (const float*)d_in[0];
  const float* Centers = (const float*)d_in[1];
  const float* W1      = (const float*)d_in[2];
  const float* b1      = (const float*)d_in[3];
  const float* W2      = (const float*)d_in[4];
  const float* b2      = (const float*)d_in[5];
  const float* W3      = (const float*)d_in[6];
  const float* b3      = (const float*)d_in[7];
  const int*   h1      = (const int*)d_in[8];
  const float* s1      = (const float*)d_in[9];
  const int*   h2      = (const int*)d_in[10];
  const float* s2      = (const float*)d_in[11];
  const float* Wc1     = (const float*)d_in[12];
  const float* bc1     = (const float*)d_in[13];
  const float* Wc2     = (const float*)d_in[14];
  const float* bc2     = (const float*)d_in[15];
  float* out = (float*)d_out;

  char* ws = (char*)d_ws;
  const size_t MB = 1u << 20;
  u16* Xb    = (u16*)(ws);
  u16* CBPb  = (u16*)(ws);
  u16* E1b   = (u16*)(ws + 64 * MB);
  u16* Zb    = (u16*)(ws + 64 * MB);
  u16* E2b   = (u16*)(ws + 96 * MB);
  u16* E3b   = (u16*)(ws + 112 * MB);
  u16* W1t   = (u16*)(ws + 120 * MB);
  u16* W2t   = (u16*)(ws + 121 * MB);
  u16* W3t   = (u16*)(ws + 121 * MB + 512 * 1024);
  u16* Wc1t  = (u16*)(ws + 122 * MB);

  const dim3 blk(256);

  // casts: X, Centers -> Xb rows [0..B), [B..2B)  (single launch)
  cast2_bf16<<<dim3(2 * CAST_NB), blk, 0, stream>>>(X, Centers, Xb);

  // weight transposes (single launch, z selects matrix)
  transpose_cast4<<<dim3(D_CBP / 32, H_C / 32, 4), blk, 0, stream>>>(
      W1, W1t, W2, W2t, W3, W3t, Wc1, Wc1t);

  // G1..G3 (embed, X and Centers batched as 2B rows)
  gemm_bf16<<<dim3(H1_DIM / 128, 2 * BATCH / 128), blk, 0, stream>>>(
      Xb, W1t, b1, E1b, 2 * BATCH, H1_DIM, D_IN);
  gemm_bf16<<<dim3(H2_DIM / 128, 2 * BATCH / 128), blk, 0, stream>>>(
      E1b, W2t, b2, E2b, 2 * BATCH, H2_DIM, H1_DIM);
  gemm_bf16<<<dim3(H3_DIM / 128, 2 * BATCH / 128), blk, 0, stream>>>(
      E2b, W3t, b3, E3b, 2 * BATCH, H3_DIM, H2_DIM);

  // CBP (sparse outer-product scatter)
  cbp_kernel<<<dim3(BATCH), blk, 0, stream>>>(E3b, h1, s1, h2, s2, CBPb);

  // G4
  gemm_bf16<<<dim3(H_C / 128, BATCH / 128), blk, 0, stream>>>(
      CBPb, Wc1t, bc1, Zb, BATCH, H_C, D_CBP);

  // head
  head_softmax<<<dim3(BATCH / 4), blk, 0, stream>>>(Zb, Wc2, bc2, out);
}

// Round 2
// 549.514 us; speedup vs baseline: 3.1878x; 3.1878x over previous
//
#include <hip/hip_runtime.h>
#include <hip/hip_bf16.h>
#include <math.h>

// ---------------------------------------------------------------------------
// Dims (fixed per reference)
// ---------------------------------------------------------------------------
#define BATCH   16384
#define D_IN    1024
#define H1_DIM  512
#define H2_DIM  256
#define H3_DIM  128
#define D_CBP   2048
#define H_C     1024
#define CLASSES 10
#define SLOPE   0.2f

typedef short v8s __attribute__((ext_vector_type(8)));
typedef float v4f __attribute__((ext_vector_type(4)));
typedef _Float16 h2v __attribute__((ext_vector_type(2)));
typedef unsigned short u16;
typedef unsigned int   u32;

__device__ __forceinline__ float b2f(unsigned short u) {
  return __uint_as_float(((unsigned)u) << 16);
}
__device__ __forceinline__ u16 f2b(float f) {
  __hip_bfloat16 h = __float2bfloat16(f);   // RNE
  return __builtin_bit_cast(unsigned short, h);
}
__device__ __forceinline__ u32 pkrtz(float lo, float hi) {
  return __builtin_bit_cast(u32, __builtin_amdgcn_cvt_pkrtz(lo, hi));
}

// async 16B global->LDS (direct-to-shared DMA). LDS dest = wave-uniform base
// + lane*16 -> LDS layout is forced packed lane-order.
__device__ __forceinline__ void g2l16(const void* g, void* l) {
  __builtin_amdgcn_global_load_lds(
      (const __attribute__((address_space(1))) void*)g,
      (__attribute__((address_space(3))) void*)l, 16, 0, 0);
}

// ---------------------------------------------------------------------------
// bf16 MFMA GEMM (m97 structure): C[M,N] = lrelu(A[M,K] @ Bt[N,K]^T + bias)
// Tile 128x128, BK=32, 256 threads (4 waves, 2x2 of 64x64), 16 MFMA/wave/step.
// Granule rotation swizzle applied at the GLOBAL address so both A- and
// B-fragment ds_read_b128 are exactly 2 lanes/bank (free).
// r2: bijective XCD-aware block swizzle (T1) — each XCD gets a contiguous
// chunk of the flattened tile space for L2 operand-panel residency.
// ---------------------------------------------------------------------------
__global__ __launch_bounds__(256) void gemm_bf16(
    const u16* __restrict__ A,   // [M][K] bf16
    const u16* __restrict__ Bt,  // [N][K] bf16  (weights pre-transposed)
    const float* __restrict__ bias,
    u16* __restrict__ C,         // [M][N] bf16
    int M, int N, int K)
{
  __shared__ __align__(16) short Asb[128 * 32];
  __shared__ __align__(16) short Bsb[128 * 32];

  const int tid  = threadIdx.x;
  const int wave = tid >> 6, lane = tid & 63;
  const int wm = wave >> 1, wn = wave & 1;
  const int u = lane & 15, quad = lane >> 4;

  // XCD swizzle: default dispatch round-robins consecutive ids across the 8
  // XCDs; remap so XCD k owns a contiguous panel [k*cpx, (k+1)*cpx).
  // Bijective iff nwg % 8 == 0 (true for all our grids; guarded anyway).
  const int nwg = gridDim.x * gridDim.y;
  int id = blockIdx.y * gridDim.x + blockIdx.x;
  if ((nwg & 7) == 0) id = (id & 7) * (nwg >> 3) + (id >> 3);
  const int m0 = (id / gridDim.x) * 128, n0 = (id % gridDim.x) * 128;

  const int g_log = ((lane & 3) - ((lane >> 3) & 3)) & 3;
  const int srow  = wave * 32 + (lane >> 2);
  const u16* gA0 = A  + (size_t)(m0 + srow)      * K + g_log * 8;
  const u16* gA1 = A  + (size_t)(m0 + srow + 16) * K + g_log * 8;
  const u16* gB0 = Bt + (size_t)(n0 + srow)      * K + g_log * 8;
  const u16* gB1 = Bt + (size_t)(n0 + srow + 16) * K + g_log * 8;
  short* lA0 = &Asb[(wave * 32)      * 32];
  short* lA1 = &Asb[(wave * 32 + 16) * 32];
  short* lB0 = &Bsb[(wave * 32)      * 32];
  short* lB1 = &Bsb[(wave * 32 + 16) * 32];

  const int gran = (quad + (u >> 1)) & 3;
  int offA[4], offB[4];
#pragma unroll
  for (int i = 0; i < 4; ++i) {
    offA[i] = (wm * 64 + i * 16 + u) * 32 + gran * 8;
    offB[i] = (wn * 64 + i * 16 + u) * 32 + gran * 8;
  }

  v4f acc[4][4];
#pragma unroll
  for (int i = 0; i < 4; ++i)
#pragma unroll
    for (int j = 0; j < 4; ++j) acc[i][j] = (v4f){0.f, 0.f, 0.f, 0.f};

  for (int k0 = 0; k0 < K; k0 += 32) {
    __syncthreads();
    g2l16(gA0 + k0, lA0);
    g2l16(gA1 + k0, lA1);
    g2l16(gB0 + k0, lB0);
    g2l16(gB1 + k0, lB1);
    __syncthreads();
    v8s a[4], b[4];
#pragma unroll
    for (int i = 0; i < 4; ++i) a[i] = *(const v8s*)&Asb[offA[i]];
#pragma unroll
    for (int j = 0; j < 4; ++j) b[j] = *(const v8s*)&Bsb[offB[j]];
#pragma unroll
    for (int i = 0; i < 4; ++i)
#pragma unroll
      for (int j = 0; j < 4; ++j)
        acc[i][j] = __builtin_amdgcn_mfma_f32_16x16x32_bf16(a[i], b[j], acc[i][j], 0, 0, 0);
  }

  // C/D layout (m89-verified): col = lane&15, row = quad*4 + reg
  float bcol[4];
#pragma unroll
  for (int j = 0; j < 4; ++j) bcol[j] = bias[n0 + wn * 64 + j * 16 + u];
#pragma unroll
  for (int i = 0; i < 4; ++i)
#pragma unroll
    for (int r = 0; r < 4; ++r) {
      const size_t ro = (size_t)(m0 + wm * 64 + i * 16 + quad * 4 + r) * N
                        + n0 + wn * 64 + u;
#pragma unroll
      for (int j = 0; j < 4; ++j) {
        float v = acc[i][j][r] + bcol[j];
        v = v >= 0.f ? v : SLOPE * v;
        C[ro + j * 16] = f2b(v);
      }
    }
}

// ---------------------------------------------------------------------------
// cast fp32 -> bf16, two sources in one launch (X then Centers)
// ---------------------------------------------------------------------------
#define CAST_NB (BATCH * D_IN / 4 / 256)   // blocks per source
__global__ __launch_bounds__(256) void cast2_bf16(
    const float* __restrict__ srcA, const float* __restrict__ srcB,
    u16* __restrict__ dst)
{
  const int bx = blockIdx.x;
  const float* s = (bx < CAST_NB) ? srcA : srcB;
  const int i = ((bx < CAST_NB) ? bx : bx - CAST_NB) * 256 + threadIdx.x;
  u16* d = dst + ((bx < CAST_NB) ? 0 : (size_t)BATCH * D_IN);
  const float4 v = ((const float4*)s)[i];
  __align__(8) u16 o[4] = {f2b(v.x), f2b(v.y), f2b(v.z), f2b(v.w)};
  *(uint2*)(d + (size_t)i * 4) = *(uint2*)o;
}

// ---------------------------------------------------------------------------
// transpose + cast, all 4 weights in one launch (z selects the matrix):
// W[K][N] fp32 -> Wt[N][K] bf16.  32x32 tiles via LDS.
// ---------------------------------------------------------------------------
__global__ __launch_bounds__(256) void transpose_cast4(
    const float* __restrict__ W1, u16* __restrict__ W1t,
    const float* __restrict__ W2, u16* __restrict__ W2t,
    const float* __restrict__ W3, u16* __restrict__ W3t,
    const float* __restrict__ Wc1, u16* __restrict__ Wc1t)
{
  __shared__ float tile[32][33];
  const int z = blockIdx.z;
  const float* W; u16* Wt; int K, N;
  if      (z == 0) { W = W1;  Wt = W1t;  K = D_IN;   N = H1_DIM; }
  else if (z == 1) { W = W2;  Wt = W2t;  K = H1_DIM; N = H2_DIM; }
  else if (z == 2) { W = W3;  Wt = W3t;  K = H2_DIM; N = H3_DIM; }
  else             { W = Wc1; Wt = Wc1t; K = D_CBP;  N = H_C;    }
  const int k0 = blockIdx.x * 32, n0 = blockIdx.y * 32;
  if (k0 >= K || n0 >= N) return;
  const int tx = threadIdx.x & 31, ty = threadIdx.x >> 5;
#pragma unroll
  for (int s = 0; s < 4; ++s) {
    const int k = ty * 4 + s;
    tile[k][tx] = W[(size_t)(k0 + k) * N + n0 + tx];
  }
  __syncthreads();
#pragma unroll
  for (int s = 0; s < 4; ++s) {
    const int n = ty * 4 + s;
    Wt[(size_t)(n0 + n) * K + k0 + tx] = f2b(tile[tx][n]);
  }
}

// ---------------------------------------------------------------------------
// Compact bilinear pooling, gather form (r0 proven version, 167 µs).
// DS pipe is the binding resource: main loop is 128 conflict-free
// ds_read_b128 per thread against the 8-rotation f16 table (rot4), built
// from a 16-float per-thread register window (4 aligned b128 reads + 8 b128
// writes — free compile-time rotations in registers).
//   bsk[q]     = sum_j s2[j]*ec[b,j]*[h2[j]==q]       (f32, tiny scatter)
//   rot4[r][g] = uint4 of f16(bsk[(8g + e - r) & 2047]), e=0..7
//   cbp[b,8t+e]= sum_i a_i * bsk[(8t + e - h1_i) & 2047]
// Main loop per i: 1 ds_read_b128 + 4 v_pk_fma_f16 with the a_i broadcast
// held in the single allowed SGPR operand ("s" constraint).
// [r1 post-mortem: sparse ds_add_f32 scatter = ~198 cyc/wave-atomic -> 8x
//  regression. Random-bank LDS atomics must never be on the critical path.]
// ---------------------------------------------------------------------------
__global__ __launch_bounds__(256) void cbp_kernel(
    const u16* __restrict__ E3,     // [2*BATCH][128] bf16
    const int* __restrict__ h1, const float* __restrict__ s1,
    const int* __restrict__ h2, const float* __restrict__ s2,
    u16* __restrict__ cbp)          // [BATCH][2048] bf16
{
  __shared__ float bsk[D_CBP];                  // 8 KiB
  __shared__ __align__(16) uint4 rot4[8][256];  // 32 KiB

  const int b = blockIdx.x, t = threadIdx.x, lane = t & 63;

  for (int q = t; q < D_CBP; q += 256) bsk[q] = 0.f;

  // a-side: value duplicated into a packed half2, two per lane
  const float a0 = b2f(E3[(size_t)b * H3_DIM + lane])      * s1[lane];
  const float a1 = b2f(E3[(size_t)b * H3_DIM + 64 + lane]) * s1[64 + lane];
  const u32 pa0 = __builtin_bit_cast(u32, (h2v){(_Float16)a0, (_Float16)a0});
  const u32 pa1 = __builtin_bit_cast(u32, (h2v){(_Float16)a1, (_Float16)a1});

  __syncthreads();
  if (t < H3_DIM) {
    const float bv = b2f(E3[(size_t)(BATCH + b) * H3_DIM + t]) * s2[t];
    atomicAdd(&bsk[h2[t]], bv);     // 128 adds, negligible contention
  }
  __syncthreads();

  // Builder: window e[k] = bsk[(8t - 8 + k) & 2047], k = 0..15 (4 aligned
  // float4 reads, consecutive lanes -> conflict-free). Rotation r of granule
  // t = entries 8t-r..8t-r+7 = e[8-r..15-r]: register selects + 4 cvt_pkrtz.
  {
    float e[16];
#pragma unroll
    for (int c = 0; c < 4; ++c) {
      const int idx = (8 * t - 8 + 4 * c) & (D_CBP - 1);
      *(float4*)&e[4 * c] = *(const float4*)&bsk[idx];
    }
#pragma unroll
    for (int r = 0; r < 8; ++r) {
      uint4 v;
      v.x = pkrtz(e[8 - r],  e[9 - r]);
      v.y = pkrtz(e[10 - r], e[11 - r]);
      v.z = pkrtz(e[12 - r], e[13 - r]);
      v.w = pkrtz(e[14 - r], e[15 - r]);
      rot4[r][t] = v;
    }
  }
  __syncthreads();

  float facc[8];
#pragma unroll
  for (int c = 0; c < 8; ++c) facc[c] = 0.f;

#pragma unroll
  for (int b16 = 0; b16 < 8; ++b16) {       // 8 chunks x 16 i
    u32 acc2[4] = {0u, 0u, 0u, 0u};         // 4x packed f16 pair accumulators
#pragma unroll
    for (int ii = 0; ii < 16; ++ii) {
      const int i = b16 * 16 + ii;
      const int h = h1[i];                  // uniform -> s_load + SALU decompose
      const u32 au = (i < 64) ? (u32)__builtin_amdgcn_readlane(pa0, i)
                              : (u32)__builtin_amdgcn_readlane(pa1, i - 64);
      const int g = (t - (h >> 3)) & 255;
      const uint4 tv = rot4[h & 7][g];
      asm("v_pk_fma_f16 %0, %1, %2, %0" : "+v"(acc2[0]) : "s"(au), "v"(tv.x));
      asm("v_pk_fma_f16 %0, %1, %2, %0" : "+v"(acc2[1]) : "s"(au), "v"(tv.y));
      asm("v_pk_fma_f16 %0, %1, %2, %0" : "+v"(acc2[2]) : "s"(au), "v"(tv.z));
      asm("v_pk_fma_f16 %0, %1, %2, %0" : "+v"(acc2[3]) : "s"(au), "v"(tv.w));
    }
#pragma unroll
    for (int c = 0; c < 4; ++c) {
      const h2v av = __builtin_bit_cast(h2v, acc2[c]);
      facc[2 * c]     += (float)av[0];
      facc[2 * c + 1] += (float)av[1];
    }
  }

  v8s ov;
#pragma unroll
  for (int c = 0; c < 8; ++c) ov[c] = (short)f2b(facc[c]);
  *(v8s*)(cbp + (size_t)b * D_CBP + t * 8) = ov;
}

// ---------------------------------------------------------------------------
// Head: logits = Z[B,1024](bf16) @ Wc2[1024,10] + bc2; softmax -> fp32 out.
// ---------------------------------------------------------------------------
__global__ __launch_bounds__(256) void head_softmax(
    const u16* __restrict__ Z, const float* __restrict__ Wc2,
    const float* __restrict__ bc2, float* __restrict__ out)
{
  const int row  = blockIdx.x * 4 + (threadIdx.x >> 6);
  const int lane = threadIdx.x & 63;

  float acc[CLASSES];
#pragma unroll
  for (int c = 0; c < CLASSES; ++c) acc[c] = 0.f;

  const u16* z = Z + (size_t)row * H_C;
  for (int k = lane; k < H_C; k += 64) {
    const float zv = b2f(z[k]);
    const float* w = Wc2 + (size_t)k * CLASSES;
#pragma unroll
    for (int c = 0; c < CLASSES; ++c) acc[c] += zv * w[c];
  }
#pragma unroll
  for (int c = 0; c < CLASSES; ++c) {
#pragma unroll
    for (int off = 32; off > 0; off >>= 1)
      acc[c] += __shfl_down(acc[c], off);
  }
  if (lane == 0) {
    float l[CLASSES], mx = -1e30f;
#pragma unroll
    for (int c = 0; c < CLASSES; ++c) { l[c] = acc[c] + bc2[c]; mx = fmaxf(mx, l[c]); }
    float s = 0.f;
#pragma unroll
    for (int c = 0; c < CLASSES; ++c) { l[c] = __expf(l[c] - mx); s += l[c]; }
    const float inv = 1.f / s;
#pragma unroll
    for (int c = 0; c < CLASSES; ++c) out[(size_t)row * CLASSES + c] = l[c] * inv;
  }
}

// ---------------------------------------------------------------------------
// Launcher.  Workspace (1 MiB = 1<<20), lifetime-packed, ~126 MiB:
//   Xb   @ 0       [32768,1024] bf16 = 64 MiB   (dead after G1)
//   CBPb @ 0       [16384,2048] bf16 = 64 MiB   (overlays Xb)
//   E1b  @ 64 MiB  [32768, 512] bf16 = 32 MiB   (dead after G2)
//   Zb   @ 64 MiB  [16384,1024] bf16 = 32 MiB   (overlays E1b)
//   E2b  @ 96 MiB  [32768, 256] bf16 = 16 MiB
//   E3b  @ 112 MiB [32768, 128] bf16 =  8 MiB
//   W1t @120M  W2t @121M  W3t @121.5M  Wc1t @122M (bf16, transposed)
// ---------------------------------------------------------------------------
extern "C" void kernel_launch(void* const* d_in, const int* in_sizes, int n_in,
                              void* d_out, int out_size, void* d_ws, size_t ws_size,
                              hipStream_t stream) {
  const float* X       = (const float*)d_in[0];
  const float* Centers = (const float*)d_in[1];
  const float* W1      = (const float*)d_in[2];
  const float* b1      = (const float*)d_in[3];
  const float* W2      = (const float*)d_in[4];
  const float* b2      = (const float*)d_in[5];
  const float* W3      = (const float*)d_in[6];
  const float* b3      = (const float*)d_in[7];
  const int*   h1      = (const int*)d_in[8];
  const float* s1      = (const float*)d_in[9];
  const int*   h2      = (const int*)d_in[10];
  const float* s2      = (const float*)d_in[11];
  const float* Wc1     = (const float*)d_in[12];
  const float* bc1     = (const float*)d_in[13];
  const float* Wc2     = (const float*)d_in[14];
  const float* bc2     = (const float*)d_in[15];
  float* out = (float*)d_out;

  char* ws = (char*)d_ws;
  const size_t MB = 1u << 20;
  u16* Xb    = (u16*)(ws);
  u16* CBPb  = (u16*)(ws);
  u16* E1b   = (u16*)(ws + 64 * MB);
  u16* Zb    = (u16*)(ws + 64 * MB);
  u16* E2b   = (u16*)(ws + 96 * MB);
  u16* E3b   = (u16*)(ws + 112 * MB);
  u16* W1t   = (u16*)(ws + 120 * MB);
  u16* W2t   = (u16*)(ws + 121 * MB);
  u16* W3t   = (u16*)(ws + 121 * MB + 512 * 1024);
  u16* Wc1t  = (u16*)(ws + 122 * MB);

  const dim3 blk(256);

  // casts: X, Centers -> Xb rows [0..B), [B..2B)  (single launch)
  cast2_bf16<<<dim3(2 * CAST_NB), blk, 0, stream>>>(X, Centers, Xb);

  // weight transposes (single launch, z selects matrix)
  transpose_cast4<<<dim3(D_CBP / 32, H_C / 32, 4), blk, 0, stream>>>(
      W1, W1t, W2, W2t, W3, W3t, Wc1, Wc1t);

  // G1..G3 (embed, X and Centers batched as 2B rows)
  gemm_bf16<<<dim3(H1_DIM / 128, 2 * BATCH / 128), blk, 0, stream>>>(
      Xb, W1t, b1, E1b, 2 * BATCH, H1_DIM, D_IN);
  gemm_bf16<<<dim3(H2_DIM / 128, 2 * BATCH / 128), blk, 0, stream>>>(
      E1b, W2t, b2, E2b, 2 * BATCH, H2_DIM, H1_DIM);
  gemm_bf16<<<dim3(H3_DIM / 128, 2 * BATCH / 128), blk, 0, stream>>>(
      E2b, W3t, b3, E3b, 2 * BATCH, H3_DIM, H2_DIM);

  // CBP (dense rot-table gather — proven)
  cbp_kernel<<<dim3(BATCH), blk, 0, stream>>>(E3b, h1, s1, h2, s2, CBPb);

  // G4
  gemm_bf16<<<dim3(H_C / 128, BATCH / 128), blk, 0, stream>>>(
      CBPb, Wc1t, bc1, Zb, BATCH, H_C, D_CBP);

  // head
  head_softmax<<<dim3(BATCH / 4), blk, 0, stream>>>(Zb, Wc2, bc2, out);
}